// Round 1
// baseline (2482.713 us; speedup 1.0000x reference)
//
#include <hip/hip_runtime.h>
#include <hip/hip_bf16.h>
#include <stdint.h>

// Problem constants
#define B_    16
#define C_IN  64
#define C_OUT 32
#define V_HI  163842
#define V_LO  40962
#define K_    7
#define TOTAL_E (V_LO * K_)            // 286734 entries in inverse map
#define NPART 641                      // ceil(V_HI/256)

// ---------------------------------------------------------------------------
// Pass 1: h[b,o,v] = sum_c x[b,c,v]*W[o,c] + bias[o]
// x: [B, C_IN, V_LO], W: [C_OUT, C_IN], h: [B, C_OUT, V_LO]
// ---------------------------------------------------------------------------
__global__ __launch_bounds__(256) void compute_h_k(
    const float* __restrict__ x, const float* __restrict__ W,
    const float* __restrict__ bias, float* __restrict__ h)
{
    __shared__ float sW[C_OUT * C_IN];   // 8 KB
    __shared__ float sB[C_OUT];
    int t = threadIdx.x;
    for (int i = t; i < C_OUT * C_IN; i += 256) sW[i] = W[i];
    if (t < C_OUT) sB[t] = bias[t];
    __syncthreads();

    int b = blockIdx.y;
    int v = blockIdx.x * 256 + t;
    if (v >= V_LO) return;

    const float* xp = x + (size_t)b * C_IN * V_LO + v;
    float acc[C_OUT];
#pragma unroll
    for (int o = 0; o < C_OUT; ++o) acc[o] = 0.0f;

    for (int c = 0; c < C_IN; ++c) {
        float xv = xp[(size_t)c * V_LO];          // coalesced across lanes
#pragma unroll
        for (int o = 0; o < C_OUT; ++o)
            acc[o] += xv * sW[o * C_IN + c];      // LDS broadcast (free)
    }

    float* hp = h + (size_t)b * C_OUT * V_LO + v;
#pragma unroll
    for (int o = 0; o < C_OUT; ++o)
        hp[(size_t)o * V_LO] = acc[o] + sB[o];
}

// ---------------------------------------------------------------------------
// Inverse-map build: for each u in [0,V_HI), list of (v,k) with
// up_neigh[down[v],k] == u.  Entries packed as (v<<3)|k (v < 65536 fits).
// ---------------------------------------------------------------------------
__global__ __launch_bounds__(256) void count_k(
    const int* __restrict__ up, const int* __restrict__ down,
    unsigned* __restrict__ cnt)
{
    int v = blockIdx.x * 256 + threadIdx.x;
    if (v >= V_LO) return;
    int d = down[v];
    const int* row = up + (size_t)d * K_;
    for (int k = 0; k < K_; ++k)
        atomicAdd(&cnt[row[k]], 1u);
}

__global__ __launch_bounds__(256) void blocksum_k(
    const unsigned* __restrict__ cnt, unsigned* __restrict__ partials)
{
    __shared__ unsigned s[256];
    int i = blockIdx.x * 256 + threadIdx.x;
    unsigned v = (i < V_HI) ? cnt[i] : 0u;
    s[threadIdx.x] = v;
    __syncthreads();
    for (int off = 128; off > 0; off >>= 1) {
        if (threadIdx.x < off) s[threadIdx.x] += s[threadIdx.x + off];
        __syncthreads();
    }
    if (threadIdx.x == 0) partials[blockIdx.x] = s[0];
}

__global__ __launch_bounds__(1024) void scanpart_k(unsigned* __restrict__ partials)
{
    __shared__ unsigned s[1024];
    int t = threadIdx.x;
    unsigned v = (t < NPART) ? partials[t] : 0u;
    s[t] = v;
    __syncthreads();
    for (int off = 1; off < 1024; off <<= 1) {
        unsigned add = (t >= off) ? s[t - off] : 0u;
        __syncthreads();
        s[t] += add;
        __syncthreads();
    }
    if (t < NPART) partials[t] = s[t] - v;   // exclusive
}

__global__ __launch_bounds__(256) void addoff_k(
    const unsigned* __restrict__ cnt, const unsigned* __restrict__ partials,
    unsigned* __restrict__ offsets, unsigned* __restrict__ cursor)
{
    __shared__ unsigned s[256];
    int t = threadIdx.x;
    int i = blockIdx.x * 256 + t;
    unsigned c = (i < V_HI) ? cnt[i] : 0u;
    s[t] = c;
    __syncthreads();
    for (int off = 1; off < 256; off <<= 1) {
        unsigned add = (t >= off) ? s[t - off] : 0u;
        __syncthreads();
        s[t] += add;
        __syncthreads();
    }
    unsigned excl = s[t] - c + partials[blockIdx.x];
    if (i < V_HI) { offsets[i] = excl; cursor[i] = excl; }
    if (i == 0) offsets[V_HI] = (unsigned)TOTAL_E;
}

__global__ __launch_bounds__(256) void scatter_k(
    const int* __restrict__ up, const int* __restrict__ down,
    unsigned* __restrict__ cursor, unsigned* __restrict__ entries)
{
    int v = blockIdx.x * 256 + threadIdx.x;
    if (v >= V_LO) return;
    int d = down[v];
    const int* row = up + (size_t)d * K_;
    for (int k = 0; k < K_; ++k) {
        int u = row[k];
        unsigned pos = atomicAdd(&cursor[u], 1u);
        entries[pos] = ((unsigned)v << 3) | (unsigned)k;
    }
}

// ---------------------------------------------------------------------------
// Pass 3: one block per (b,o) pair. For each u: scan candidates, pick the
// max v whose mp[b,o,v]==k, emit h[b,o,v] (or 0).  Order-independent of the
// atomic entry order, so deterministic across graph replays.
// ---------------------------------------------------------------------------
__global__ __launch_bounds__(1024) void gather_out_k(
    const unsigned* __restrict__ offsets, const unsigned* __restrict__ entries,
    const int* __restrict__ mp, const float* __restrict__ h,
    float* __restrict__ out)
{
    int pair = blockIdx.x;                       // b*C_OUT + o
    const int*   mpp = mp  + (size_t)pair * V_LO;
    const float* hp  = h   + (size_t)pair * V_LO;
    float*       op  = out + (size_t)pair * V_HI;

    for (int u = threadIdx.x; u < V_HI; u += 1024) {
        unsigned s0 = offsets[u];
        unsigned s1 = offsets[u + 1];
        int best = -1;
        for (unsigned e = s0; e < s1; ++e) {
            unsigned p = entries[e];
            int v = (int)(p >> 3);
            int k = (int)(p & 7u);
            if (mpp[v] == k && v > best) best = v;
        }
        op[u] = (best >= 0) ? hp[best] : 0.0f;
    }
}

// ---------------------------------------------------------------------------
extern "C" void kernel_launch(void* const* d_in, const int* in_sizes, int n_in,
                              void* d_out, int out_size, void* d_ws, size_t ws_size,
                              hipStream_t stream)
{
    const float* x    = (const float*)d_in[0];
    const float* W    = (const float*)d_in[1];
    const float* bias = (const float*)d_in[2];
    const int*   mp   = (const int*)d_in[3];
    const int*   up   = (const int*)d_in[4];
    const int*   down = (const int*)d_in[5];
    float* out = (float*)d_out;

    // Workspace layout (bytes)
    char* ws = (char*)d_ws;
    const size_t H_BYTES   = (size_t)B_ * C_OUT * V_LO * sizeof(float);   // 83,890,176
    const size_t CNT_OFF   = H_BYTES;
    const size_t OFF_OFF   = CNT_OFF + (size_t)V_HI * 4;
    const size_t CUR_OFF   = OFF_OFF + (size_t)(V_HI + 1) * 4;
    const size_t ENT_OFF   = CUR_OFF + (size_t)V_HI * 4;
    const size_t PART_OFF  = ENT_OFF + (size_t)TOTAL_E * 4;

    float*    h       = (float*)ws;
    unsigned* cnt     = (unsigned*)(ws + CNT_OFF);
    unsigned* offsets = (unsigned*)(ws + OFF_OFF);
    unsigned* cursor  = (unsigned*)(ws + CUR_OFF);
    unsigned* entries = (unsigned*)(ws + ENT_OFF);
    unsigned* partials= (unsigned*)(ws + PART_OFF);

    // zero the count array (workspace is poisoned 0xAA every call)
    hipMemsetAsync(cnt, 0, (size_t)V_HI * 4, stream);

    // Pass 1: h
    {
        dim3 grid((V_LO + 255) / 256, B_);
        compute_h_k<<<grid, 256, 0, stream>>>(x, W, bias, h);
    }

    // Inverse map build
    {
        int vblk = (V_LO + 255) / 256;           // 161
        count_k<<<vblk, 256, 0, stream>>>(up, down, cnt);
        blocksum_k<<<NPART, 256, 0, stream>>>(cnt, partials);
        scanpart_k<<<1, 1024, 0, stream>>>(partials);
        addoff_k<<<NPART, 256, 0, stream>>>(cnt, partials, offsets, cursor);
        scatter_k<<<vblk, 256, 0, stream>>>(up, down, cursor, entries);
    }

    // Pass 3: output
    gather_out_k<<<B_ * C_OUT, 1024, 0, stream>>>(offsets, entries, mp, h, out);
}

// Round 2
// 1030.307 us; speedup vs baseline: 2.4097x; 2.4097x over previous
//
#include <hip/hip_runtime.h>
#include <hip/hip_bf16.h>
#include <stdint.h>

// Problem constants
#define B_    16
#define C_IN  64
#define C_OUT 32
#define V_HI  163842
#define V_LO  40962
#define K_    7
#define TOTAL_E (V_LO * K_)            // 286734 entries in inverse map
#define NPART 641                      // ceil(V_HI/256)

// LDS layout for gather: mp bytes [0,40968) , h bf16 [40968, 40968+81924)
#define S_MP_BYTES 40968               // V_LO padded to 8
#define GATHER_LDS (S_MP_BYTES + V_LO * 2 + 4)   // 122896 < 163840

// ---------------------------------------------------------------------------
// Pass 1: h[b,o,v] = sum_c x[b,c,v]*W[o,c] + bias[o], stored as bf16
// ---------------------------------------------------------------------------
__global__ __launch_bounds__(256) void compute_h_k(
    const float* __restrict__ x, const float* __restrict__ W,
    const float* __restrict__ bias, __hip_bfloat16* __restrict__ h)
{
    __shared__ float sW[C_OUT * C_IN];   // 8 KB
    __shared__ float sB[C_OUT];
    int t = threadIdx.x;
    for (int i = t; i < C_OUT * C_IN; i += 256) sW[i] = W[i];
    if (t < C_OUT) sB[t] = bias[t];
    __syncthreads();

    int b = blockIdx.y;
    int v = blockIdx.x * 256 + t;
    if (v >= V_LO) return;

    const float* xp = x + (size_t)b * C_IN * V_LO + v;
    float acc[C_OUT];
#pragma unroll
    for (int o = 0; o < C_OUT; ++o) acc[o] = 0.0f;

    for (int c = 0; c < C_IN; ++c) {
        float xv = xp[(size_t)c * V_LO];          // coalesced across lanes
#pragma unroll
        for (int o = 0; o < C_OUT; ++o)
            acc[o] += xv * sW[o * C_IN + c];      // LDS broadcast (free)
    }

    __hip_bfloat16* hp = h + (size_t)b * C_OUT * V_LO + v;
#pragma unroll
    for (int o = 0; o < C_OUT; ++o)
        hp[(size_t)o * V_LO] = __float2bfloat16(acc[o] + sB[o]);
}

// ---------------------------------------------------------------------------
// Inverse-map build: for each u in [0,V_HI), list of (v,k) with
// up_neigh[down[v],k] == u.  Entries packed as (v<<3)|k.
// ---------------------------------------------------------------------------
__global__ __launch_bounds__(256) void count_k(
    const int* __restrict__ up, const int* __restrict__ down,
    unsigned* __restrict__ cnt)
{
    int v = blockIdx.x * 256 + threadIdx.x;
    if (v >= V_LO) return;
    int d = down[v];
    const int* row = up + (size_t)d * K_;
    for (int k = 0; k < K_; ++k)
        atomicAdd(&cnt[row[k]], 1u);
}

__global__ __launch_bounds__(256) void blocksum_k(
    const unsigned* __restrict__ cnt, unsigned* __restrict__ partials)
{
    __shared__ unsigned s[256];
    int i = blockIdx.x * 256 + threadIdx.x;
    unsigned v = (i < V_HI) ? cnt[i] : 0u;
    s[threadIdx.x] = v;
    __syncthreads();
    for (int off = 128; off > 0; off >>= 1) {
        if (threadIdx.x < off) s[threadIdx.x] += s[threadIdx.x + off];
        __syncthreads();
    }
    if (threadIdx.x == 0) partials[blockIdx.x] = s[0];
}

__global__ __launch_bounds__(1024) void scanpart_k(unsigned* __restrict__ partials)
{
    __shared__ unsigned s[1024];
    int t = threadIdx.x;
    unsigned v = (t < NPART) ? partials[t] : 0u;
    s[t] = v;
    __syncthreads();
    for (int off = 1; off < 1024; off <<= 1) {
        unsigned add = (t >= off) ? s[t - off] : 0u;
        __syncthreads();
        s[t] += add;
        __syncthreads();
    }
    if (t < NPART) partials[t] = s[t] - v;   // exclusive
}

__global__ __launch_bounds__(256) void addoff_k(
    const unsigned* __restrict__ cnt, const unsigned* __restrict__ partials,
    unsigned* __restrict__ offsets, unsigned* __restrict__ cursor)
{
    __shared__ unsigned s[256];
    int t = threadIdx.x;
    int i = blockIdx.x * 256 + t;
    unsigned c = (i < V_HI) ? cnt[i] : 0u;
    s[t] = c;
    __syncthreads();
    for (int off = 1; off < 256; off <<= 1) {
        unsigned add = (t >= off) ? s[t - off] : 0u;
        __syncthreads();
        s[t] += add;
        __syncthreads();
    }
    unsigned excl = s[t] - c + partials[blockIdx.x];
    if (i < V_HI) { offsets[i] = excl; cursor[i] = excl; }
    if (i == 0) offsets[V_HI] = (unsigned)TOTAL_E;
}

__global__ __launch_bounds__(256) void scatter_k(
    const int* __restrict__ up, const int* __restrict__ down,
    unsigned* __restrict__ cursor, unsigned* __restrict__ entries)
{
    int v = blockIdx.x * 256 + threadIdx.x;
    if (v >= V_LO) return;
    int d = down[v];
    const int* row = up + (size_t)d * K_;
    for (int k = 0; k < K_; ++k) {
        int u = row[k];
        unsigned pos = atomicAdd(&cursor[u], 1u);
        entries[pos] = ((unsigned)v << 3) | (unsigned)k;
    }
}

// ---------------------------------------------------------------------------
// Pass 3: one block per (b,o) pair. Stage mp (as bytes) and h (bf16) slices
// in LDS so all scattered reads stay on-CU. For each u: scan candidates,
// pick max v with mp[v]==k, emit h[v] (or 0). Order-independent of the
// atomic entry order, so deterministic across graph replays.
// ---------------------------------------------------------------------------
__global__ __launch_bounds__(1024) void gather_out_k(
    const unsigned* __restrict__ offsets, const unsigned* __restrict__ entries,
    const int* __restrict__ mp, const ushort* __restrict__ h,
    float* __restrict__ out)
{
    extern __shared__ char smem[];
    unsigned char* s_mp = (unsigned char*)smem;            // 40962 bytes
    ushort*        s_h  = (ushort*)(smem + S_MP_BYTES);    // 40962 bf16

    int pair = blockIdx.x;                       // b*C_OUT + o
    const int*    mpp = mp  + (size_t)pair * V_LO;
    const ushort* hp  = h   + (size_t)pair * V_LO;
    float*        op  = out + (size_t)pair * V_HI;

    for (int i = threadIdx.x; i < V_LO; i += 1024) {
        s_mp[i] = (unsigned char)mpp[i];   // coalesced global read
        s_h[i]  = hp[i];                   // coalesced global read
    }
    __syncthreads();

    for (int u = threadIdx.x; u < V_HI; u += 1024) {
        unsigned s0 = offsets[u];
        unsigned s1 = offsets[u + 1];
        int best = -1;
        for (unsigned e = s0; e < s1; ++e) {
            unsigned p = entries[e];
            int v = (int)(p >> 3);
            int k = (int)(p & 7u);
            if (s_mp[v] == (unsigned char)k && v > best) best = v;
        }
        float r = 0.0f;
        if (best >= 0)
            r = __uint_as_float(((unsigned)s_h[best]) << 16);  // bf16 -> f32
        op[u] = r;                          // coalesced full-line writes
    }
}

// ---------------------------------------------------------------------------
extern "C" void kernel_launch(void* const* d_in, const int* in_sizes, int n_in,
                              void* d_out, int out_size, void* d_ws, size_t ws_size,
                              hipStream_t stream)
{
    const float* x    = (const float*)d_in[0];
    const float* W    = (const float*)d_in[1];
    const float* bias = (const float*)d_in[2];
    const int*   mp   = (const int*)d_in[3];
    const int*   up   = (const int*)d_in[4];
    const int*   down = (const int*)d_in[5];
    float* out = (float*)d_out;

    // Workspace layout (bytes)
    char* ws = (char*)d_ws;
    const size_t H_BYTES   = (size_t)B_ * C_OUT * V_LO * sizeof(__hip_bfloat16); // 41,945,088
    const size_t CNT_OFF   = H_BYTES;
    const size_t OFF_OFF   = CNT_OFF + (size_t)V_HI * 4;
    const size_t CUR_OFF   = OFF_OFF + (size_t)(V_HI + 1) * 4;
    const size_t ENT_OFF   = CUR_OFF + (size_t)V_HI * 4;
    const size_t PART_OFF  = ENT_OFF + (size_t)TOTAL_E * 4;

    __hip_bfloat16* h = (__hip_bfloat16*)ws;
    unsigned* cnt     = (unsigned*)(ws + CNT_OFF);
    unsigned* offsets = (unsigned*)(ws + OFF_OFF);
    unsigned* cursor  = (unsigned*)(ws + CUR_OFF);
    unsigned* entries = (unsigned*)(ws + ENT_OFF);
    unsigned* partials= (unsigned*)(ws + PART_OFF);

    // opt in to >64KB dynamic LDS for the gather kernel (idempotent, no-op
    // if already set; does not enqueue stream work so graph-capture safe)
    (void)hipFuncSetAttribute((const void*)gather_out_k,
                              hipFuncAttributeMaxDynamicSharedMemorySize,
                              GATHER_LDS);

    // zero the count array (workspace is poisoned 0xAA every call)
    hipMemsetAsync(cnt, 0, (size_t)V_HI * 4, stream);

    // Pass 1: h
    {
        dim3 grid((V_LO + 255) / 256, B_);
        compute_h_k<<<grid, 256, 0, stream>>>(x, W, bias, h);
    }

    // Inverse map build
    {
        int vblk = (V_LO + 255) / 256;           // 161
        count_k<<<vblk, 256, 0, stream>>>(up, down, cnt);
        blocksum_k<<<NPART, 256, 0, stream>>>(cnt, partials);
        scanpart_k<<<1, 1024, 0, stream>>>(partials);
        addoff_k<<<NPART, 256, 0, stream>>>(cnt, partials, offsets, cursor);
        scatter_k<<<vblk, 256, 0, stream>>>(up, down, cursor, entries);
    }

    // Pass 3: output
    gather_out_k<<<B_ * C_OUT, 1024, GATHER_LDS, stream>>>(offsets, entries, mp, (const ushort*)h, out);
}